// Round 1
// 19716.705 us; speedup vs baseline: 1.0057x; 1.0057x over previous
//
#include <hip/hip_runtime.h>

// GRU decoder B=64,T=512,IN=H=512,L=2. Persistent pipelined grid:
//   blocks [0,128)  = cell A (layer0 @ t),  blocks [128,256) = cell B (layer1 @ t-1)
// 256 blocks x 512 threads (8 waves/CU, 2/SIMD). Block = 4 cols; wave = 4 cols x K-octant.
// h-state in d_ws, [k][b] layout, written with sc0sc1 (write-through to L3 = coherence
// point), read with normal cached loads after a per-tick acquire fence (buffer_inv).
// Barrier: per-block monotonic slots (no atomic RMW contention); wave0 polls+min-reduces.
//
// R1 change: WEIGHTS LIVE IN LDS. Each block's 48KB weight slice (4 cols x 3 gates x
// {Wih,Whh} x K=512) is staged into LDS once at startup. The per-tick acquire fence
// invalidates vL1+L2+K$, which previously forced ~49KB/block of cold scalar weight
// loads every tick (the latency chain that left VALUBusy at 18.6%). LDS weight reads
// are broadcast ds_read_b128 (conflict-free), immune to the invalidate.

#define NBLK 256
#define NTHR 512
#define Bsz  64
#define Tlen 512
#define Kd   512
#define Hd   512
#define KC   64
#define LP   67   // LDS pitch: scalar transpose writes land 2-way max (free)

__device__ __forceinline__ float sigf(float v){ return 1.0f/(1.0f+__expf(-v)); }
__device__ __forceinline__ float tanhx(float v){
  float e=__expf(-2.0f*fabsf(v)); float t=(1.0f-e)/(1.0f+e); return v<0.0f?-t:t;
}
__device__ __forceinline__ unsigned umin2(unsigned a, unsigned b){ return a<b?a:b; }

// coherent (L2-bypassing, L3-committed) store/load
__device__ __forceinline__ void st_coh(float* p, float v){
  asm volatile("global_store_dword %0, %1, off sc0 sc1" :: "v"(p), "v"(v) : "memory");
}
__device__ __forceinline__ void st_coh_u(unsigned* p, unsigned v){
  asm volatile("global_store_dword %0, %1, off sc0 sc1" :: "v"(p), "v"(v) : "memory");
}
__device__ __forceinline__ void wait_vm0(){ asm volatile("s_waitcnt vmcnt(0)" ::: "memory"); }

// Grid barrier: release = (sc0sc1 data stores) + vmcnt(0) + slot store.
// acquire = poll slots via coherent loads, then agent acquire fence (inv L1/L2)
// so subsequent NORMAL loads see fresh h. Weights live in LDS (untouched by inv).
__device__ __forceinline__ void grid_barrier(unsigned* slots, unsigned target, int tid){
  wait_vm0();                 // every wave: my coherent stores are committed at L3
  __syncthreads();            // whole block done storing
  if(tid == 0) st_coh_u(slots + blockIdx.x, target);
  if(tid < 64){
    const unsigned* p0 = slots + tid;
    for(;;){
      unsigned a,b,c,d;
      asm volatile(
        "global_load_dword %0, %4, off sc0 sc1\n\t"
        "global_load_dword %1, %5, off sc0 sc1\n\t"
        "global_load_dword %2, %6, off sc0 sc1\n\t"
        "global_load_dword %3, %7, off sc0 sc1\n\t"
        "s_waitcnt vmcnt(0)"
        : "=v"(a),"=v"(b),"=v"(c),"=v"(d)
        : "v"(p0), "v"(p0+64), "v"(p0+128), "v"(p0+192)
        : "memory");
      unsigned m = umin2(umin2(a,b), umin2(c,d));
      #pragma unroll
      for(int off=32; off; off>>=1)
        m = umin2(m, (unsigned)__shfl_xor((int)m, off, 64));
      if(m >= target) break;
      __builtin_amdgcn_s_sleep(1);
    }
  }
  __syncthreads();
  __builtin_amdgcn_fence(__ATOMIC_ACQUIRE, "agent");  // inv vL1+L2 -> normal loads fresh
}

// stage+transpose chunk ch of x[b][t][.] into sbuf[k_local][b], pitch LP
__device__ __forceinline__ void stageA(float* sbuf, const float* __restrict__ x,
                                       int t, int ch, int tid){
  #pragma unroll
  for(int it=0; it<2; ++it){
    int q  = it*NTHR + tid;          // 0..1023
    int b  = q >> 4;
    int k4 = (q & 15) << 2;
    const float4 v = *(const float4*)(x + ((size_t)b*Tlen + t)*Kd + ch*KC + k4);
    sbuf[(k4+0)*LP + b] = v.x;
    sbuf[(k4+1)*LP + b] = v.y;
    sbuf[(k4+2)*LP + b] = v.z;
    sbuf[(k4+3)*LP + b] = v.w;
  }
}

// 4-k-step of all 24 weight streams from LDS (broadcast b128 reads), FMA order
// bit-identical to the original per-k sequence: for each k (=u): c-loop of
// {xv*Wi_r, xv*Wi_z, xv*Wi_n, hv*Wh_r, hv*Wh_z, hv*Wh_n}.
__device__ __forceinline__ void gru_fma(const float* __restrict__ wlds, int kg,
                                        const float* xv, const float* hv,
                                        float* pr, float* pz, float* pni, float* pnh)
{
  float4 w[24];
  #pragma unroll
  for(int s = 0; s < 24; ++s)
    w[s] = *(const float4*)(wlds + s*Kd + kg);
  #pragma unroll
  for(int u = 0; u < 4; ++u){
    #pragma unroll
    for(int c = 0; c < 4; ++c){
      pr[c]  = fmaf(xv[u], (&w[     c].x)[u], pr[c]);
      pz[c]  = fmaf(xv[u], (&w[ 4 + c].x)[u], pz[c]);
      pni[c] = fmaf(xv[u], (&w[ 8 + c].x)[u], pni[c]);
      pr[c]  = fmaf(hv[u], (&w[12 + c].x)[u], pr[c]);
      pz[c]  = fmaf(hv[u], (&w[16 + c].x)[u], pz[c]);
      pnh[c] = fmaf(hv[u], (&w[20 + c].x)[u], pnh[c]);
    }
  }
}

extern "C" __global__ void __launch_bounds__(NTHR, 2)
gru_persist(const float* __restrict__ x,     // [B,T,IN]
            const float* __restrict__ eh,    // [L,B,H]
            const float* __restrict__ Wih,   // [L,3H,IN]
            const float* __restrict__ Whh,   // [L,3H,H]
            const float* __restrict__ bih,   // [L,3H]
            const float* __restrict__ bhh,   // [L,3H]
            float* __restrict__ out,         // [B,T,H] ++ [L,B,H]
            float* __restrict__ ws)
{
  __shared__ float smem[2*KC*LP];   // A: x staging dbuf; reused as reduction buffer
  __shared__ float wlds[24*Kd];     // 48KB: this block's weights, stream s = mat*12+g*4+c

  unsigned* slots = (unsigned*)ws;            // 256 monotonic tick slots
  float* h0T = ws + 256;                      // 2 bufs x [512][64]
  float* h1T = h0T + 2*Kd*Bsz;
  float* htail = out + (size_t)Bsz*Tlen*Hd;

  const int tid  = threadIdx.x;
  const int lane = tid & 63;                                   // batch
  const int wv   = __builtin_amdgcn_readfirstlane(tid >> 6);   // wave id 0..7
  const int cell = blockIdx.x >> 7;                            // 0=layer0, 1=layer1
  const int cb   = blockIdx.x & 127;
  const int col0 = cb * 4;                                     // block's 4 cols
  unsigned bar = 1;

  // ---- one-time: stage this block's 24 weight rows into LDS ----
  {
    const float* WiC = Wih + (size_t)cell*3*Hd*Kd;
    const float* WhC = Whh + (size_t)cell*3*Hd*Kd;
    #pragma unroll 1
    for(int i = tid; i < 24*(Kd/4); i += NTHR){  // 3072 float4s, 6 iters/thread
      const int s   = i >> 7;                    // stream 0..23
      const int k4  = (i & 127) << 2;
      const int mat = (s >= 12);
      const int r   = s - 12*mat;
      const int g   = r >> 2, c = r & 3;
      const float* src = (mat ? WhC : WiC) + ((size_t)(g*Hd + col0 + c))*Kd + k4;
      *(float4*)(wlds + (size_t)s*Kd + k4) = *(const float4*)src;
    }
  }

  // ---- init: encoder_h -> parity-1 state bufs, transposed [k][b], coherent ----
  {
    int i = blockIdx.x*NTHR + tid;            // 131072 threads, 65536 items
    if(i < 2*Kd*Bsz){
      int l = i >> 15, k = (i >> 6) & 511, b = i & 63;
      float v = eh[(size_t)(l*Bsz + b)*Hd + k];
      st_coh((l ? h1T : h0T) + Kd*Bsz + k*Bsz + b, v);
    }
  }
  grid_barrier(slots, bar, tid); bar++;       // also fences wlds staging for this block

  // epilogue biases for this wave's col (clamped for waves 4..7; unused there)
  const int ec = wv & 3;
  const int ecol = col0 + ec;
  const float bi0 = bih[cell*1536 + 0*Hd + ecol] + bhh[cell*1536 + 0*Hd + ecol];
  const float bi1 = bih[cell*1536 + 1*Hd + ecol] + bhh[cell*1536 + 1*Hd + ecol];
  const float bi2 = bih[cell*1536 + 2*Hd + ecol];
  const float bh2 = bhh[cell*1536 + 2*Hd + ecol];

  for(int t = 0; t <= Tlen; ++t){
    const bool active = (cell == 0) ? (t < Tlen) : (t >= 1);
    if(active){
      const int s = (cell == 0) ? t : (t - 1);
      float* hbase = (cell == 0) ? h0T : h1T;
      const float* hprev = hbase + ((s+1)&1)*Kd*Bsz;
      float*       hout  = hbase + (s&1)*Kd*Bsz;
      const float* inT   = h0T + (s&1)*Kd*Bsz;      // cell B input (just written by A)

      float pr[4]={0,0,0,0}, pz[4]={0,0,0,0}, pni[4]={0,0,0,0}, pnh[4]={0,0,0,0};

      if(cell == 0){
        // x via LDS transpose (chunked, double-buffered); h direct global (cached);
        // weights broadcast from LDS.
        stageA(smem, x, t, 0, tid);
        __syncthreads();
        for(int ch = 0; ch < 8; ++ch){
          const float* cur = smem + (ch&1)*(KC*LP);
          if(ch < 7) stageA(smem + ((ch+1)&1)*(KC*LP), x, t, ch+1, tid);
          #pragma unroll
          for(int jj = 0; jj < 8; jj += 4){
            const int kl = (wv<<3) + jj;         // wave's interleaved sub-slice
            const int kg = (ch<<6) + kl;
            float xv[4], hv[4];
            #pragma unroll
            for(int u = 0; u < 4; ++u){
              xv[u] = cur[(kl+u)*LP + lane];
              hv[u] = hprev[(kg+u)*Bsz + lane];
            }
            gru_fma(wlds, kg, xv, hv, pr, pz, pni, pnh);
          }
          __syncthreads();
        }
      } else {
        // both act streams direct from [k][b] global (coalesced, L2-cached);
        // weights broadcast from LDS. Manual 1-group software pipeline on h/x loads.
        const int kg0 = (wv<<6);                 // contiguous K-octant
        float xv[4], hv[4], xn[4], hn[4];
        #pragma unroll
        for(int u = 0; u < 4; ++u){
          xv[u] = inT[(kg0+u)*Bsz + lane];
          hv[u] = hprev[(kg0+u)*Bsz + lane];
        }
        #pragma unroll 1
        for(int j4 = 0; j4 < 60; j4 += 4){
          const int kg = kg0 + j4;
          #pragma unroll
          for(int u = 0; u < 4; ++u){
            xn[u] = inT[(kg+4+u)*Bsz + lane];
            hn[u] = hprev[(kg+4+u)*Bsz + lane];
          }
          gru_fma(wlds, kg, xv, hv, pr, pz, pni, pnh);
          #pragma unroll
          for(int u = 0; u < 4; ++u){ xv[u] = xn[u]; hv[u] = hn[u]; }
        }
        gru_fma(wlds, kg0 + 60, xv, hv, pr, pz, pni, pnh);
        __syncthreads();   // match A's pre-reduction state (smem free)
      }

      // ---- ksplit-8 reduction via LDS (aliases smem; guarded by syncs) ----
      float* red = smem;   // [(c*4+p)*8 + w][64]
      #pragma unroll
      for(int c = 0; c < 4; ++c){
        red[(((c<<2)+0)*8 + wv)*64 + lane] = pr[c];
        red[(((c<<2)+1)*8 + wv)*64 + lane] = pz[c];
        red[(((c<<2)+2)*8 + wv)*64 + lane] = pni[c];
        red[(((c<<2)+3)*8 + wv)*64 + lane] = pnh[c];
      }
      __syncthreads();
      if(wv < 4){
        const int c = wv;
        float spr=0.f, spz=0.f, spni=0.f, spnh=0.f;
        #pragma unroll
        for(int w = 0; w < 8; ++w){
          spr  += red[(((c<<2)+0)*8 + w)*64 + lane];
          spz  += red[(((c<<2)+1)*8 + w)*64 + lane];
          spni += red[(((c<<2)+2)*8 + w)*64 + lane];
          spnh += red[(((c<<2)+3)*8 + w)*64 + lane];
        }
        const int col = col0 + c;
        const float hkeep = hprev[col*Bsz + lane];
        const float r = sigf(spr + bi0);
        const float z = sigf(spz + bi1);
        const float n = tanhx(spni + bi2 + r*(spnh + bh2));
        const float hnew = (1.0f - z)*n + z*hkeep;
        st_coh(hout + col*Bsz + lane, hnew);                       // coherent, 256B/wave
        if(cell == 1)
          out[((size_t)lane*Tlen + s)*Hd + col] = hnew;            // normal store
      }
    }
    grid_barrier(slots, bar, tid); bar++;
  }

  // ---- tail: htail[l][b][c] from parity-1 bufs (post-fence normal loads) ----
  {
    int i = blockIdx.x*NTHR + tid;
    if(i < 2*Kd*Bsz){
      int l = i >> 15, b = (i >> 9) & 63, c = i & 511;
      const float* src = (l ? h1T : h0T) + Kd*Bsz;
      htail[i] = src[c*Bsz + b];
    }
  }
}

extern "C" void kernel_launch(void* const* d_in, const int* in_sizes, int n_in,
                              void* d_out, int out_size, void* d_ws, size_t ws_size,
                              hipStream_t stream) {
  (void)in_sizes; (void)n_in; (void)out_size; (void)ws_size;
  const float* x   = (const float*)d_in[0];
  const float* eh  = (const float*)d_in[1];
  const float* Wih = (const float*)d_in[2];
  const float* Whh = (const float*)d_in[3];
  const float* bih = (const float*)d_in[4];
  const float* bhh = (const float*)d_in[5];
  float* out = (float*)d_out;
  float* ws  = (float*)d_ws;

  hipMemsetAsync(d_ws, 0, 1024, stream);   // zero barrier slots

  void* args[] = {(void*)&x, (void*)&eh, (void*)&Wih, (void*)&Whh,
                  (void*)&bih, (void*)&bhh, (void*)&out, (void*)&ws};
  hipLaunchCooperativeKernel((const void*)gru_persist, dim3(NBLK), dim3(NTHR),
                             args, 0, stream);
}